// Round 7
// baseline (216.022 us; speedup 1.0000x reference)
//
#include <hip/hip_runtime.h>
#include <math.h>
#include <stdint.h>

#define NPTS 8192
#define TOPK 30
#define BUF2SZ 768
#define SENT 0xFFFFFFFFFFFFFFFFULL

// Exact numpy-order key: (float_bits(D) << 32) | j, numpy association order,
// no fma contraction. Unsigned compare == stable top_k order. (Verified r2-r6.)
__device__ __forceinline__ unsigned long long exact_key(const float* __restrict__ X,
                                                        float xi, float yi, float zi, int j) {
#pragma clang fp contract(off)
    float dx = X[j * 3 + 0] - xi;
    float dy = X[j * 3 + 1] - yi;
    float dz = X[j * 3 + 2] - zi;
    float d2 = dx * dx;
    d2 = d2 + dy * dy;
    d2 = d2 + dz * dz;
    float d = sqrtf(d2 + 1e-6f);
    return ((unsigned long long)__float_as_uint(d) << 32) | (unsigned int)j;
}

__device__ __forceinline__ unsigned long long bcast64(unsigned long long v, int src) {
    return (unsigned long long)__shfl((long long)v, src);
}

__global__ __launch_bounds__(256, 8)
void knn_topk_kernel(const float* __restrict__ X,
                     const float* __restrict__ mask,
                     float* __restrict__ out)
{
    __shared__ int buf2[4][BUF2SZ];   // 12.3 KB total -> 8 blocks/CU

    const int lane = threadIdx.x & 63;
    const int wv   = threadIdx.x >> 6;
    const int row  = (int)(blockIdx.x << 2) | wv;

    const float xi = X[row * 3 + 0];
    const float yi = X[row * 3 + 1];
    const float zi = X[row * 3 + 2];

    // ---- phase 0: T = 20th smallest of 64 per-lane minima over points
    // 0..511 (contiguous block: coalesced reads, identical across waves ->
    // L1-hot; iid data so any block is an unbiased sample). E[C] ~ 350. ----
    float smin = INFINITY;
#pragma unroll
    for (int k = 0; k < 8; ++k) {
        const int j = lane + (k << 6);
        const float dx = X[j * 3 + 0] - xi;
        const float dy = X[j * 3 + 1] - yi;
        const float dz = X[j * 3 + 2] - zi;
        smin = fminf(smin, fmaf(dz, dz, fmaf(dy, dy, dx * dx)));
    }
#pragma unroll
    for (int k = 2; k <= 64; k <<= 1) {
#pragma unroll
        for (int m = k >> 1; m >= 1; m >>= 1) {
            const float p = __shfl_xor(smin, m);
            const bool take_min = (((lane & k) == 0) == ((lane & m) == 0));
            smin = ((smin < p) == take_min) ? smin : p;
        }
    }
    float T = __shfl(smin, 19);           // 20th smallest (ascending by lane)

    // ---- phase 1: fixed-T scan; pass/fail kept as REGISTER BITMASKS.
    // Lane owns candidates t*256 + lane*4 + k; bit (t&7)*4+k of word t>>3.
    // No LDS, no cross-lane ops, no per-candidate bookkeeping. ----
    const float4* X4 = (const float4*)X;
    unsigned m0, m1, m2, m3;
    int cnt, C;

#define SCAN8(MREG, TBASE)                                                     \
    {                                                                          \
        unsigned cm = 0;                                                       \
        _Pragma("unroll")                                                      \
        for (int t8 = 0; t8 < 8; ++t8) {                                       \
            const int t = (TBASE) + t8;                                        \
            const int bi = (t * 64 + lane) * 3;                                \
            const float4 a0 = X4[bi + 0];                                      \
            const float4 a1 = X4[bi + 1];                                      \
            const float4 a2 = X4[bi + 2];                                      \
            const float dx0 = a0.x - xi, dy0 = a0.y - yi, dz0 = a0.z - zi;     \
            const float dx1 = a0.w - xi, dy1 = a1.x - yi, dz1 = a1.y - zi;     \
            const float dx2 = a1.z - xi, dy2 = a1.w - yi, dz2 = a2.x - zi;     \
            const float dx3 = a2.y - xi, dy3 = a2.z - yi, dz3 = a2.w - zi;     \
            const float q0 = fmaf(dz0, dz0, fmaf(dy0, dy0, dx0 * dx0));        \
            const float q1 = fmaf(dz1, dz1, fmaf(dy1, dy1, dx1 * dx1));        \
            const float q2 = fmaf(dz2, dz2, fmaf(dy2, dy2, dx2 * dx2));        \
            const float q3 = fmaf(dz3, dz3, fmaf(dy3, dy3, dx3 * dx3));        \
            unsigned nib = (q0 < T) ? 1u : 0u;                                 \
            nib |= (q1 < T) ? 2u : 0u;                                         \
            nib |= (q2 < T) ? 4u : 0u;                                         \
            nib |= (q3 < T) ? 8u : 0u;                                         \
            cm |= nib << (t8 * 4);                                             \
        }                                                                      \
        MREG = cm;                                                             \
    }

    for (;;) {
        SCAN8(m0, 0)
        SCAN8(m1, 8)
        SCAN8(m2, 16)
        SCAN8(m3, 24)
        cnt = __popc(m0) + __popc(m1) + __popc(m2) + __popc(m3);
        C = cnt;
#pragma unroll
        for (int d = 32; d; d >>= 1) C += __shfl_xor(C, d);
        if (C >= 33 && C <= BUF2SZ) break;    // wave-uniform; rescans ~0/launch
        T = (C < 33) ? T * 2.0f : T * 0.5f;
    }
#undef SCAN8

    // ---- materialize candidate indices once: prefix-scan + bit extraction ----
    int s = cnt;
#pragma unroll
    for (int d = 1; d < 64; d <<= 1) {
        const int n = __shfl_up(s, d);
        if (lane >= d) s += n;
    }
    int off = s - cnt;

#define EXTRACT(MREG, TBASE)                                                   \
    {                                                                          \
        unsigned mm = (MREG);                                                  \
        while (mm) {                                                           \
            const int b = __builtin_ctz(mm);                                   \
            mm &= mm - 1;                                                      \
            const int t = (TBASE) + (b >> 2);                                  \
            buf2[wv][off++] = t * 256 + (lane << 2) + (b & 3);                 \
        }                                                                      \
    }
    EXTRACT(m0, 0)
    EXTRACT(m1, 8)
    EXTRACT(m2, 16)
    EXTRACT(m3, 24)
#undef EXTRACT

    // ---- phase 2: exact top-30 (chunk bitonic sort + merge, verified) ----
    unsigned long long list = SENT;
    for (int s0 = 0; s0 < C; s0 += 64) {
        const int sc = s0 + lane;
        unsigned long long ck = SENT;
        if (sc < C) ck = exact_key(X, xi, yi, zi, buf2[wv][sc]);

#pragma unroll
        for (int k = 2; k <= 64; k <<= 1) {
#pragma unroll
            for (int m = k >> 1; m >= 1; m >>= 1) {
                const unsigned long long p = (unsigned long long)__shfl_xor((long long)ck, m);
                const bool take_min = (((lane & k) == 0) == ((lane & m) == 0));
                ck = ((ck < p) == take_min) ? ck : p;
            }
        }

        const unsigned long long cg = bcast64(ck, 63 - lane);
        unsigned long long v = (lane < TOPK) ? list : cg;
#pragma unroll
        for (int m = 32; m >= 1; m >>= 1) {
            const unsigned long long p = (unsigned long long)__shfl_xor((long long)v, m);
            const bool low = ((lane & m) == 0);
            v = (low == (v < p)) ? v : p;
        }
        list = (lane < TOPK) ? v : SENT;
    }

    // ---- emit ----
    if (lane < TOPK) {
        const int   li = (int)(uint32_t)(list & 0xFFFFFFFFu);
        const float lv = __uint_as_float((uint32_t)(list >> 32));
        const int base = row * TOPK + lane;
        out[base]                   = lv;                    // D_neighbors
        out[NPTS * TOPK + base]     = (float)li;             // E_idx
        out[2 * NPTS * TOPK + base] = mask[row] * mask[li];  // mask_neighbors
    }
}

extern "C" void kernel_launch(void* const* d_in, const int* in_sizes, int n_in,
                              void* d_out, int out_size, void* d_ws, size_t ws_size,
                              hipStream_t stream) {
    const float* X    = (const float*)d_in[0];
    const float* mask = (const float*)d_in[1];
    float* out        = (float*)d_out;

    dim3 grid(NPTS / 4), block(256);   // one wave per row; 2048 blocks = 8/CU
    knn_topk_kernel<<<grid, block, 0, stream>>>(X, mask, out);
}

// Round 8
// 135.354 us; speedup vs baseline: 1.5960x; 1.5960x over previous
//
#include <hip/hip_runtime.h>
#include <math.h>
#include <stdint.h>

#define NPTS 8192
#define TOPK 30
#define BUF2SZ 768
#define SENT 0xFFFFFFFFFFFFFFFFULL

// Exact numpy-order key: (float_bits(D) << 32) | j, numpy association order,
// no fma contraction. Unsigned compare == stable top_k order. (Verified r2-r7.)
__device__ __forceinline__ unsigned long long exact_key(const float* __restrict__ X,
                                                        float xi, float yi, float zi, int j) {
#pragma clang fp contract(off)
    float dx = X[j * 3 + 0] - xi;
    float dy = X[j * 3 + 1] - yi;
    float dz = X[j * 3 + 2] - zi;
    float d2 = dx * dx;
    d2 = d2 + dy * dy;
    d2 = d2 + dz * dz;
    float d = sqrtf(d2 + 1e-6f);
    return ((unsigned long long)__float_as_uint(d) << 32) | (unsigned int)j;
}

__device__ __forceinline__ unsigned long long bcast64(unsigned long long v, int src) {
    return (unsigned long long)__shfl((long long)v, src);
}

// NOTE: no min-waves arg — round 7 proved __launch_bounds__(256,8) forces a
// 64-VGPR cap -> 280 MB of scratch spill traffic. Let the allocator breathe.
__global__ __launch_bounds__(256)
void knn_topk_kernel(const float* __restrict__ X,
                     const float* __restrict__ mask,
                     float* __restrict__ out)
{
    __shared__ int buf2[4][BUF2SZ];   // 12.3 KB/block

    const int lane = threadIdx.x & 63;
    const int wv   = threadIdx.x >> 6;
    const int row  = (int)(blockIdx.x << 2) | wv;

    const float xi = X[row * 3 + 0];
    const float yi = X[row * 3 + 1];
    const float zi = X[row * 3 + 2];

    // ---- phase 0: T = 20th smallest of 64 per-lane minima over points
    // 0..511 (contiguous -> coalesced + L1-hot; iid data -> unbiased). ----
    float smin = INFINITY;
#pragma unroll
    for (int k = 0; k < 8; ++k) {
        const int j = lane + (k << 6);
        const float dx = X[j * 3 + 0] - xi;
        const float dy = X[j * 3 + 1] - yi;
        const float dz = X[j * 3 + 2] - zi;
        smin = fminf(smin, fmaf(dz, dz, fmaf(dy, dy, dx * dx)));
    }
#pragma unroll
    for (int k = 2; k <= 64; k <<= 1) {
#pragma unroll
        for (int m = k >> 1; m >= 1; m >>= 1) {
            const float p = __shfl_xor(smin, m);
            const bool take_min = (((lane & k) == 0) == ((lane & m) == 0));
            smin = ((smin < p) == take_min) ? smin : p;
        }
    }
    float T = __shfl(smin, 19);           // 20th smallest; E[C] ~ 350

    // ---- phase 1: fixed-T scan, pass/fail as register bitmasks.
    // Lane owns candidates t*256 + lane*4 + k; nibble per t, 8 t's per word.
    // Unroll 4 per half-word: ~12 live float4 -> no spill pressure. ----
    const float4* X4 = (const float4*)X;
    unsigned msk[8];
    int cnt, C;

    for (;;) {
        cnt = 0;
#pragma unroll
        for (int w = 0; w < 8; ++w) {
            unsigned cm = 0;
#pragma unroll
            for (int t4 = 0; t4 < 4; ++t4) {
                const int t = w * 4 + t4;
                const int bi = (t * 64 + lane) * 3;
                const float4 a0 = X4[bi + 0];
                const float4 a1 = X4[bi + 1];
                const float4 a2 = X4[bi + 2];
                const float dx0 = a0.x - xi, dy0 = a0.y - yi, dz0 = a0.z - zi;
                const float dx1 = a0.w - xi, dy1 = a1.x - yi, dz1 = a1.y - zi;
                const float dx2 = a1.z - xi, dy2 = a1.w - yi, dz2 = a2.x - zi;
                const float dx3 = a2.y - xi, dy3 = a2.z - yi, dz3 = a2.w - zi;
                const float q0 = fmaf(dz0, dz0, fmaf(dy0, dy0, dx0 * dx0));
                const float q1 = fmaf(dz1, dz1, fmaf(dy1, dy1, dx1 * dx1));
                const float q2 = fmaf(dz2, dz2, fmaf(dy2, dy2, dx2 * dx2));
                const float q3 = fmaf(dz3, dz3, fmaf(dy3, dy3, dx3 * dx3));
                unsigned nib = (q0 < T) ? 1u : 0u;
                nib |= (q1 < T) ? 2u : 0u;
                nib |= (q2 < T) ? 4u : 0u;
                nib |= (q3 < T) ? 8u : 0u;
                cm |= nib << (t4 * 4);
            }
            msk[w] = cm;
            cnt += __popc(cm);
        }
        C = cnt;
#pragma unroll
        for (int d = 32; d; d >>= 1) C += __shfl_xor(C, d);
        if (C >= 33 && C <= BUF2SZ) break;    // wave-uniform; rescans ~0
        T = (C < 33) ? T * 2.0f : T * 0.5f;
    }

    // ---- materialize candidate indices: prefix-scan + bit extraction ----
    int s = cnt;
#pragma unroll
    for (int d = 1; d < 64; d <<= 1) {
        const int n = __shfl_up(s, d);
        if (lane >= d) s += n;
    }
    int off = s - cnt;

#pragma unroll
    for (int w = 0; w < 8; ++w) {
        unsigned mm = msk[w];
        while (mm) {
            const int b = __builtin_ctz(mm);
            mm &= mm - 1;
            const int t = w * 4 + (b >> 2);
            buf2[wv][off++] = t * 256 + (lane << 2) + (b & 3);
        }
    }

    // ---- phase 2: exact top-30 (chunk bitonic sort + merge, verified) ----
    unsigned long long list = SENT;
    for (int s0 = 0; s0 < C; s0 += 64) {
        const int sc = s0 + lane;
        unsigned long long ck = SENT;
        if (sc < C) ck = exact_key(X, xi, yi, zi, buf2[wv][sc]);

#pragma unroll
        for (int k = 2; k <= 64; k <<= 1) {
#pragma unroll
            for (int m = k >> 1; m >= 1; m >>= 1) {
                const unsigned long long p = (unsigned long long)__shfl_xor((long long)ck, m);
                const bool take_min = (((lane & k) == 0) == ((lane & m) == 0));
                ck = ((ck < p) == take_min) ? ck : p;
            }
        }

        const unsigned long long cg = bcast64(ck, 63 - lane);
        unsigned long long v = (lane < TOPK) ? list : cg;
#pragma unroll
        for (int m = 32; m >= 1; m >>= 1) {
            const unsigned long long p = (unsigned long long)__shfl_xor((long long)v, m);
            const bool low = ((lane & m) == 0);
            v = (low == (v < p)) ? v : p;
        }
        list = (lane < TOPK) ? v : SENT;
    }

    // ---- emit ----
    if (lane < TOPK) {
        const int   li = (int)(uint32_t)(list & 0xFFFFFFFFu);
        const float lv = __uint_as_float((uint32_t)(list >> 32));
        const int base = row * TOPK + lane;
        out[base]                   = lv;                    // D_neighbors
        out[NPTS * TOPK + base]     = (float)li;             // E_idx
        out[2 * NPTS * TOPK + base] = mask[row] * mask[li];  // mask_neighbors
    }
}

extern "C" void kernel_launch(void* const* d_in, const int* in_sizes, int n_in,
                              void* d_out, int out_size, void* d_ws, size_t ws_size,
                              hipStream_t stream) {
    const float* X    = (const float*)d_in[0];
    const float* mask = (const float*)d_in[1];
    float* out        = (float*)d_out;

    dim3 grid(NPTS / 4), block(256);   // one wave per row
    knn_topk_kernel<<<grid, block, 0, stream>>>(X, mask, out);
}

// Round 10
// 113.586 us; speedup vs baseline: 1.9018x; 1.1916x over previous
//
#include <hip/hip_runtime.h>
#include <math.h>
#include <stdint.h>

#define NPTS 8192
#define TOPK 30
#define BUF2SZ 768
#define SENT 0xFFFFFFFFFFFFFFFFULL

// Exact numpy-order key: (float_bits(D) << 32) | j, numpy association order,
// no fma contraction. Unsigned compare == stable top_k order. (Verified r2-r8.)
__device__ __forceinline__ unsigned long long exact_key(const float* __restrict__ X,
                                                        float xi, float yi, float zi, int j) {
#pragma clang fp contract(off)
    float dx = X[j * 3 + 0] - xi;
    float dy = X[j * 3 + 1] - yi;
    float dz = X[j * 3 + 2] - zi;
    float d2 = dx * dx;
    d2 = d2 + dy * dy;
    d2 = d2 + dz * dz;
    float d = sqrtf(d2 + 1e-6f);
    return ((unsigned long long)__float_as_uint(d) << 32) | (unsigned int)j;
}

__device__ __forceinline__ unsigned long long bcast64(unsigned long long v, int src) {
    return (unsigned long long)__shfl((long long)v, src);
}

// No min-waves arg (r7: forcing 8/EU caused 280 MB spill traffic).
__global__ __launch_bounds__(256)
void knn_topk_kernel(const float* __restrict__ X,
                     const float* __restrict__ mask,
                     float* __restrict__ out)
{
    __shared__ int buf2[4][BUF2SZ];   // 12.3 KB/block

    const int lane = threadIdx.x & 63;
    const int wv   = threadIdx.x >> 6;
    const int row  = (int)(blockIdx.x << 2) | wv;

    const float xi = X[row * 3 + 0];
    const float yi = X[row * 3 + 1];
    const float zi = X[row * 3 + 2];

    // ---- phase 0: sample points 0..511 (coalesced, L1-hot, iid-unbiased);
    // T = 7th smallest of the 64 per-lane minima. E[C] ~ 112 +- 45. ----
    float smin = INFINITY;
#pragma unroll
    for (int k = 0; k < 8; ++k) {
        const int j = lane + (k << 6);
        const float dx = X[j * 3 + 0] - xi;
        const float dy = X[j * 3 + 1] - yi;
        const float dz = X[j * 3 + 2] - zi;
        smin = fminf(smin, fmaf(dz, dz, fmaf(dy, dy, dx * dx)));
    }
#pragma unroll
    for (int k = 2; k <= 64; k <<= 1) {
#pragma unroll
        for (int m = k >> 1; m >= 1; m >>= 1) {
            const float p = __shfl_xor(smin, m);
            const bool take_min = (((lane & k) == 0) == ((lane & m) == 0));
            smin = ((smin < p) == take_min) ? smin : p;
        }
    }
    float T = __shfl(smin, 6);            // 7th smallest (ascending by lane)

    // ---- certified retry loop: scan -> bounds check -> exact phase 2 ->
    // completeness certificate. All decisions wave-uniform. ----
    const float4* X4 = (const float4*)X;
    unsigned long long list;

    for (;;) {
        // -- fixed-T scan; pass/fail as register bitmasks (4 words x 8 nibbles).
        // Hand-pipelined: preload t+1 while computing t -> ~6 live float4.
        unsigned msk[4];
        int cnt = 0;
        {
            int bi = lane * 3;
            float4 a0 = X4[bi + 0], a1 = X4[bi + 1], a2 = X4[bi + 2];
#pragma unroll
            for (int w = 0; w < 4; ++w) {
                unsigned cm = 0;
#pragma unroll
                for (int t8 = 0; t8 < 8; ++t8) {
                    const int t = (w << 3) + t8;
                    float4 b0, b1, b2;
                    if (t < 31) {                      // compile-time branch
                        const int nbi = ((t + 1) * 64 + lane) * 3;
                        b0 = X4[nbi + 0]; b1 = X4[nbi + 1]; b2 = X4[nbi + 2];
                    } else { b0 = a0; b1 = a1; b2 = a2; }

                    const float dx0 = a0.x - xi, dy0 = a0.y - yi, dz0 = a0.z - zi;
                    const float dx1 = a0.w - xi, dy1 = a1.x - yi, dz1 = a1.y - zi;
                    const float dx2 = a1.z - xi, dy2 = a1.w - yi, dz2 = a2.x - zi;
                    const float dx3 = a2.y - xi, dy3 = a2.z - yi, dz3 = a2.w - zi;
                    const float q0 = fmaf(dz0, dz0, fmaf(dy0, dy0, dx0 * dx0));
                    const float q1 = fmaf(dz1, dz1, fmaf(dy1, dy1, dx1 * dx1));
                    const float q2 = fmaf(dz2, dz2, fmaf(dy2, dy2, dx2 * dx2));
                    const float q3 = fmaf(dz3, dz3, fmaf(dy3, dy3, dx3 * dx3));
                    unsigned nib = (q0 < T) ? 1u : 0u;
                    nib |= (q1 < T) ? 2u : 0u;
                    nib |= (q2 < T) ? 4u : 0u;
                    nib |= (q3 < T) ? 8u : 0u;
                    cm |= nib << (t8 * 4);
                    a0 = b0; a1 = b1; a2 = b2;
                }
                msk[w] = cm;
                cnt += __popc(cm);
            }
        }
        int C = cnt;
#pragma unroll
        for (int d = 32; d; d >>= 1) C += __shfl_xor(C, d);

        if (C < 33)     { T *= 2.0f; continue; }   // ~4% of waves, once
        if (C > BUF2SZ) { T *= 0.5f; continue; }   // ~never

        // -- materialize candidate indices: prefix-scan + bit extraction
        int s = cnt;
#pragma unroll
        for (int d = 1; d < 64; d <<= 1) {
            const int n = __shfl_up(s, d);
            if (lane >= d) s += n;
        }
        int off = s - cnt;
#pragma unroll
        for (int w = 0; w < 4; ++w) {
            unsigned mm = msk[w];
            while (mm) {
                const int b = __builtin_ctz(mm);
                mm &= mm - 1;
                const int t = (w << 3) + (b >> 2);
                buf2[wv][off++] = t * 256 + (lane << 2) + (b & 3);
            }
        }

        // -- phase 2: exact top-30 (chunk bitonic sort + merge, verified)
        list = SENT;
        for (int s0 = 0; s0 < C; s0 += 64) {
            const int sc = s0 + lane;
            unsigned long long ck = SENT;
            if (sc < C) ck = exact_key(X, xi, yi, zi, buf2[wv][sc]);
#pragma unroll
            for (int k = 2; k <= 64; k <<= 1) {
#pragma unroll
                for (int m = k >> 1; m >= 1; m >>= 1) {
                    const unsigned long long p = (unsigned long long)__shfl_xor((long long)ck, m);
                    const bool take_min = (((lane & k) == 0) == ((lane & m) == 0));
                    ck = ((ck < p) == take_min) ? ck : p;
                }
            }
            const unsigned long long cg = bcast64(ck, 63 - lane);
            unsigned long long v = (lane < TOPK) ? list : cg;
#pragma unroll
            for (int m = 32; m >= 1; m >>= 1) {
                const unsigned long long p = (unsigned long long)__shfl_xor((long long)v, m);
                const bool low = ((lane & m) == 0);
                v = (low == (v < p)) ? v : p;
            }
            list = (lane < TOPK) ? v : SENT;
        }

        // -- completeness certificate: every excluded j has q_fma >= T, so
        // q_np >= T(1-3e-7); if D30^2 - 1e-6 < T*0.99995 then D_np(j) > D30
        // strictly (with >2 ulp margin) -> numpy-top-30 subset of candidates.
        const float D30 = __uint_as_float((uint32_t)(bcast64(list, TOPK - 1) >> 32));
        if (fmaf(D30, D30, -1e-6f) < T * 0.99995f) break;
        T *= 2.0f;                                  // provably-safe fallback
    }

    // ---- emit ----
    if (lane < TOPK) {
        const int   li = (int)(uint32_t)(list & 0xFFFFFFFFu);
        const float lv = __uint_as_float((uint32_t)(list >> 32));
        const int base = row * TOPK + lane;
        out[base]                   = lv;                    // D_neighbors
        out[NPTS * TOPK + base]     = (float)li;             // E_idx
        out[2 * NPTS * TOPK + base] = mask[row] * mask[li];  // mask_neighbors
    }
}

extern "C" void kernel_launch(void* const* d_in, const int* in_sizes, int n_in,
                              void* d_out, int out_size, void* d_ws, size_t ws_size,
                              hipStream_t stream) {
    const float* X    = (const float*)d_in[0];
    const float* mask = (const float*)d_in[1];
    float* out        = (float*)d_out;

    dim3 grid(NPTS / 4), block(256);   // one wave per row
    knn_topk_kernel<<<grid, block, 0, stream>>>(X, mask, out);
}

// Round 11
// 97.109 us; speedup vs baseline: 2.2245x; 1.1697x over previous
//
#include <hip/hip_runtime.h>
#include <math.h>
#include <stdint.h>

#define NPTS 8192
#define TOPK 30
#define BUF2SZ 768
#define SENT 0xFFFFFFFFFFFFFFFFULL

// Exact numpy-order key: (float_bits(D) << 32) | j, numpy association order,
// no fma contraction. Unsigned compare == stable top_k order. (Verified r2-r10.)
__device__ __forceinline__ unsigned long long exact_key(const float* __restrict__ X,
                                                        float xi, float yi, float zi, int j) {
#pragma clang fp contract(off)
    float dx = X[j * 3 + 0] - xi;
    float dy = X[j * 3 + 1] - yi;
    float dz = X[j * 3 + 2] - zi;
    float d2 = dx * dx;
    d2 = d2 + dy * dy;
    d2 = d2 + dz * dz;
    float d = sqrtf(d2 + 1e-6f);
    return ((unsigned long long)__float_as_uint(d) << 32) | (unsigned int)j;
}

__device__ __forceinline__ unsigned long long bcast64(unsigned long long v, int src) {
    return (unsigned long long)__shfl((long long)v, src);
}

// No min-waves arg (r7: forcing it caused 280 MB spill). No manual pipelining
// (r10: ballooned VGPR to 108 -> 2 dispatch rounds -> 17% occupancy).
__global__ __launch_bounds__(256)
void knn_topk_kernel(const float* __restrict__ X,
                     const float* __restrict__ mask,
                     float* __restrict__ out)
{
    __shared__ int buf2[4][BUF2SZ];   // 12.3 KB/block

    const int lane = threadIdx.x & 63;
    const int wv   = threadIdx.x >> 6;
    const int row  = (int)(blockIdx.x << 2) | wv;

    const float xi = X[row * 3 + 0];
    const float yi = X[row * 3 + 1];
    const float zi = X[row * 3 + 2];

    // ---- phase 0: sample points 0..511 (coalesced, L1-hot, iid-unbiased);
    // T = 7th smallest of the 64 per-lane minima. E[C] ~ 112 +- 45. ----
    float smin = INFINITY;
#pragma unroll
    for (int k = 0; k < 8; ++k) {
        const int j = lane + (k << 6);
        const float dx = X[j * 3 + 0] - xi;
        const float dy = X[j * 3 + 1] - yi;
        const float dz = X[j * 3 + 2] - zi;
        smin = fminf(smin, fmaf(dz, dz, fmaf(dy, dy, dx * dx)));
    }
#pragma unroll
    for (int k = 2; k <= 64; k <<= 1) {
#pragma unroll
        for (int m = k >> 1; m >= 1; m >>= 1) {
            const float p = __shfl_xor(smin, m);
            const bool take_min = (((lane & k) == 0) == ((lane & m) == 0));
            smin = ((smin < p) == take_min) ? smin : p;
        }
    }
    float T = __shfl(smin, 6);            // 7th smallest (ascending by lane)

    const float4* X4 = (const float4*)X;
    unsigned long long list;

    // Scan 8 tiles (t8=0..7) for one mask word. unroll 2: <=6 live float4,
    // keeps total VGPR under the 8-waves/SIMD budget (r5 proof: this loop
    // shape compiles lean when the compiler schedules the loads itself).
#define SCANW(MREG, WBASE)                                                     \
    {                                                                          \
        unsigned cm = 0;                                                       \
        _Pragma("unroll 2")                                                    \
        for (int t8 = 0; t8 < 8; ++t8) {                                       \
            const int t = (WBASE) + t8;                                        \
            const int bi = (t * 64 + lane) * 3;                                \
            const float4 a0 = X4[bi + 0];                                      \
            const float4 a1 = X4[bi + 1];                                      \
            const float4 a2 = X4[bi + 2];                                      \
            const float dx0 = a0.x - xi, dy0 = a0.y - yi, dz0 = a0.z - zi;     \
            const float dx1 = a0.w - xi, dy1 = a1.x - yi, dz1 = a1.y - zi;     \
            const float dx2 = a1.z - xi, dy2 = a1.w - yi, dz2 = a2.x - zi;     \
            const float dx3 = a2.y - xi, dy3 = a2.z - yi, dz3 = a2.w - zi;     \
            const float q0 = fmaf(dz0, dz0, fmaf(dy0, dy0, dx0 * dx0));        \
            const float q1 = fmaf(dz1, dz1, fmaf(dy1, dy1, dx1 * dx1));        \
            const float q2 = fmaf(dz2, dz2, fmaf(dy2, dy2, dx2 * dx2));        \
            const float q3 = fmaf(dz3, dz3, fmaf(dy3, dy3, dx3 * dx3));        \
            unsigned nib = (q0 < T) ? 1u : 0u;                                 \
            nib |= (q1 < T) ? 2u : 0u;                                         \
            nib |= (q2 < T) ? 4u : 0u;                                         \
            nib |= (q3 < T) ? 8u : 0u;                                         \
            cm |= nib << (t8 * 4);                                             \
        }                                                                      \
        MREG = cm;                                                             \
        cnt += __popc(cm);                                                     \
    }

#define EXTRACTW(MREG, WBASE)                                                  \
    {                                                                          \
        unsigned mm = (MREG);                                                  \
        while (mm) {                                                           \
            const int b = __builtin_ctz(mm);                                   \
            mm &= mm - 1;                                                      \
            const int t = (WBASE) + (b >> 2);                                  \
            buf2[wv][off++] = t * 256 + (lane << 2) + (b & 3);                 \
        }                                                                      \
    }

    // ---- certified retry loop (all decisions wave-uniform) ----
    for (;;) {
        // -- fixed-T scan; pass/fail as 4 statically-named register bitmasks
        unsigned msk0, msk1, msk2, msk3;
        int cnt = 0;
        SCANW(msk0, 0)
        SCANW(msk1, 8)
        SCANW(msk2, 16)
        SCANW(msk3, 24)

        int C = cnt;
#pragma unroll
        for (int d = 32; d; d >>= 1) C += __shfl_xor(C, d);

        if (C < 33)     { T *= 2.0f; continue; }   // ~4% of waves, once
        if (C > BUF2SZ) { T *= 0.5f; continue; }   // ~never

        // -- materialize candidate indices: prefix-scan + bit extraction
        int s = cnt;
#pragma unroll
        for (int d = 1; d < 64; d <<= 1) {
            const int n = __shfl_up(s, d);
            if (lane >= d) s += n;
        }
        int off = s - cnt;
        EXTRACTW(msk0, 0)
        EXTRACTW(msk1, 8)
        EXTRACTW(msk2, 16)
        EXTRACTW(msk3, 24)

        // -- phase 2: exact top-30 (chunk bitonic sort + merge, verified)
        list = SENT;
        for (int s0 = 0; s0 < C; s0 += 64) {
            const int sc = s0 + lane;
            unsigned long long ck = SENT;
            if (sc < C) ck = exact_key(X, xi, yi, zi, buf2[wv][sc]);
#pragma unroll
            for (int k = 2; k <= 64; k <<= 1) {
#pragma unroll
                for (int m = k >> 1; m >= 1; m >>= 1) {
                    const unsigned long long p = (unsigned long long)__shfl_xor((long long)ck, m);
                    const bool take_min = (((lane & k) == 0) == ((lane & m) == 0));
                    ck = ((ck < p) == take_min) ? ck : p;
                }
            }
            const unsigned long long cg = bcast64(ck, 63 - lane);
            unsigned long long v = (lane < TOPK) ? list : cg;
#pragma unroll
            for (int m = 32; m >= 1; m >>= 1) {
                const unsigned long long p = (unsigned long long)__shfl_xor((long long)v, m);
                const bool low = ((lane & m) == 0);
                v = (low == (v < p)) ? v : p;
            }
            list = (lane < TOPK) ? v : SENT;
        }

        // -- completeness certificate: every excluded j has q_fma >= T, so
        // q_np >= T(1-3e-7); if D30^2 - 1e-6 < T*0.99995 then D_np(j) > D30
        // strictly (with >2 ulp margin) -> numpy-top-30 subset of candidates.
        const float D30 = __uint_as_float((uint32_t)(bcast64(list, TOPK - 1) >> 32));
        if (fmaf(D30, D30, -1e-6f) < T * 0.99995f) break;
        T *= 2.0f;                                  // provably-safe fallback
    }
#undef SCANW
#undef EXTRACTW

    // ---- emit ----
    if (lane < TOPK) {
        const int   li = (int)(uint32_t)(list & 0xFFFFFFFFu);
        const float lv = __uint_as_float((uint32_t)(list >> 32));
        const int base = row * TOPK + lane;
        out[base]                   = lv;                    // D_neighbors
        out[NPTS * TOPK + base]     = (float)li;             // E_idx
        out[2 * NPTS * TOPK + base] = mask[row] * mask[li];  // mask_neighbors
    }
}

extern "C" void kernel_launch(void* const* d_in, const int* in_sizes, int n_in,
                              void* d_out, int out_size, void* d_ws, size_t ws_size,
                              hipStream_t stream) {
    const float* X    = (const float*)d_in[0];
    const float* mask = (const float*)d_in[1];
    float* out        = (float*)d_out;

    dim3 grid(NPTS / 4), block(256);   // one wave per row; 8 blocks/CU
    knn_topk_kernel<<<grid, block, 0, stream>>>(X, mask, out);
}